// Round 5
// baseline (260.021 us; speedup 1.0000x reference)
//
#include <hip/hip_runtime.h>
#include <hip/hip_bf16.h>

typedef unsigned short u16;
typedef short s16x8 __attribute__((ext_vector_type(8)));
typedef float f32x4 __attribute__((ext_vector_type(4)));
typedef float f32x16 __attribute__((ext_vector_type(16)));

#define MFMA_BF16(a, b, c) __builtin_amdgcn_mfma_f32_16x16x32_bf16((a), (b), (c), 0, 0, 0)
#define MFMA32(a, b, c)    __builtin_amdgcn_mfma_f32_32x32x16_bf16((a), (b), (c), 0, 0, 0)

static constexpr int D_IN   = 64;
static constexpr int H_DIM  = 512;
static constexpr int M_TILE = 64;
static constexpr int AST    = 520;  // row stride (bf16); b128 A-reads land uniformly
                                    // across banks (structural minimum, conflict-free)
static constexpr int XST    = 72;   // x-tile row stride (144B rows, 16B-aligned)

__device__ __forceinline__ u16 f2bf(float f) {
  unsigned u = __builtin_bit_cast(unsigned, f);
  u += 0x7fffu + ((u >> 16) & 1u);   // RNE
  return (u16)(u >> 16);
}
__device__ __forceinline__ float bfb2f(unsigned bits16) {
  return __builtin_bit_cast(float, bits16 << 16);
}
__device__ __forceinline__ float fast_tanh(float x) {
  float e = __expf(2.0f * x);
  return 1.0f - 2.0f * __builtin_amdgcn_rcpf(e + 1.0f);
}
__device__ __forceinline__ f32x16 zero16() {
  f32x16 z = {0.f,0.f,0.f,0.f,0.f,0.f,0.f,0.f,0.f,0.f,0.f,0.f,0.f,0.f,0.f,0.f};
  return z;
}

// ---- prep: fp32 weights -> bf16, packed in MFMA-B-fragment order ----
// 32x32x16 B-frag pack (p0f, p1f/p1b, p2f/p2b): chunk (nt32, k16) holds 512
// elems, lane l elem j -> B[k = k16*16 + (l>>5)*8 + j][n = nt32*32 + (l&31)].
// fwd: B = W (K=rows, N=cols); bwd: B = W^T (B[k][n] = W[n][k]).
// Chunk order: nt32 * K16MAX + k16 (K16MAX: W0 fwd = 4, else 32).
// p0b keeps the OLD 16x16x32-style pack (consumed only by GEMM5).
__global__ __launch_bounds__(256) void prep_weights(const float* __restrict__ W0,
                                                    const float* __restrict__ W1,
                                                    const float* __restrict__ W2,
                                                    u16* __restrict__ ws) {
  u16* p0f = ws;                       // fwd W0: K=64,  N=512 (32-pack)
  u16* p0b = p0f + D_IN * H_DIM;       // bwd W0^T: K=512, N=64 (16-pack, GEMM5)
  u16* p1f = p0b + D_IN * H_DIM;
  u16* p1b = p1f + H_DIM * H_DIM;
  u16* p2f = p1b + H_DIM * H_DIM;
  u16* p2b = p2f + H_DIM * H_DIM;

  __shared__ __align__(16) u16 tile[64 * 72];   // 9.0 KB, stride 72 u16 (144B)

  int b = blockIdx.x;
  const float* src;
  u16 *dstf, *dstb;
  int rb, cb;
  bool isW0;
  if (b < 64) {
    src = W1; dstf = p1f; dstb = p1b; rb = b >> 3; cb = b & 7; isW0 = false;
  } else if (b < 128) {
    src = W2; dstf = p2f; dstb = p2b; rb = (b - 64) >> 3; cb = (b - 64) & 7; isW0 = false;
  } else {
    src = W0; dstf = p0f; dstb = p0b; rb = 0; cb = b - 128; isW0 = true;
  }

  const int tid = threadIdx.x;

  // ---- stage 64x64 fp32 tile -> bf16 LDS (coalesced: 4x float4 per thread) ----
  {
    int r = tid >> 2, cc = (tid & 3) * 16;
    const float4* s4 = (const float4*)(src + (size_t)(rb * 64 + r) * 512 + cb * 64 + cc);
    unsigned pk[8];
    #pragma unroll
    for (int v = 0; v < 4; ++v) {
      float4 f = s4[v];
      pk[v * 2]     = (unsigned)f2bf(f.x) | ((unsigned)f2bf(f.y) << 16);
      pk[v * 2 + 1] = (unsigned)f2bf(f.z) | ((unsigned)f2bf(f.w) << 16);
    }
    uint4* d = (uint4*)(tile + r * 72 + cc);
    d[0] = make_uint4(pk[0], pk[1], pk[2], pk[3]);
    d[1] = make_uint4(pk[4], pk[5], pk[6], pk[7]);
  }
  __syncthreads();

  // 32-style decomposition: each thread emits 16 u16 (= 2 lanes x 8 elems).
  const int cl    = tid >> 5;        // 0..7
  const int nt32l = cl >> 2;         // 0..1: which 32-col group of this tile
  const int k16l  = cl & 3;          // 0..3: which 16-row group of this tile
  const int ls    = (tid & 31) * 2;  // even lane slot; thread does ls, ls+1
  const int q5    = ls >> 5;         // same for both lanes (ls even)
  const int l31   = ls & 31;         // even

  // ---- fwd pack (32-style): elem j <- tile[k16l*16+q5*8+j][nt32l*32+l31+p] ----
  {
    __align__(16) u16 o[16];
    #pragma unroll
    for (int p = 0; p < 2; ++p)
      #pragma unroll
      for (int j = 0; j < 8; ++j)
        o[p * 8 + j] = tile[(k16l * 16 + q5 * 8 + j) * 72 + nt32l * 32 + l31 + p];
    int K16MAX = isW0 ? 4 : 32;
    int chunk = (2 * cb + nt32l) * K16MAX + (4 * rb + k16l);
    u16* dp = dstf + ((size_t)chunk * 64 + ls) * 8;
    *(uint4*)dp       = *(const uint4*)o;
    *(uint4*)(dp + 8) = *(const uint4*)(o + 8);
  }

  if (!isW0) {
    // ---- bwd pack (32-style): elem j <- W[n][k] = tile[nt32l*32+l31+p][k16l*16+q5*8+j] ----
    const u16* rp = tile + (nt32l * 32 + l31) * 72 + k16l * 16 + q5 * 8;
    s16x8 r0 = *(const s16x8*)rp;
    s16x8 r1 = *(const s16x8*)(rp + 72);
    int chunk = (2 * rb + nt32l) * 32 + (4 * cb + k16l);
    u16* dp = dstb + ((size_t)chunk * 64 + ls) * 8;
    *(s16x8*)dp       = r0;
    *(s16x8*)(dp + 8) = r1;
  } else {
    // ---- W0 bwd pack (OLD 16-style, for GEMM5) ----
    const int c   = tid >> 6;          // 0..3 (p0b has N=64 -> ntg 0..3)
    const int kcl = (tid >> 5) & 1;
    const int ls2 = (tid * 2) & 63;
    const int q   = ls2 >> 4;
    const int ln  = ls2 & 15;
    const u16* rp = tile + (c * 16 + ln) * 72 + kcl * 32 + q * 8;
    s16x8 r0 = *(const s16x8*)rp;
    s16x8 r1 = *(const s16x8*)(rp + 72);
    int kc = 2 * cb + kcl;
    u16* dp = dstb + ((size_t)(c * 16 + kc) * 64 + ls2) * 8;
    *(s16x8*)dp       = r0;
    *(s16x8*)(dp + 8) = r1;
  }
}

// Load this wave's 2 B-frags (nt32 = 2*wave, 2*wave+1) of k-step KS into VGPRs.
// Each frag = contiguous 1KB per wave, L2-resident.
#define LOAD_B2(BP, KS, BR)                                                     \
  {                                                                             \
    const u16* _sr = (BP) + ((size_t)wave << 15) + ((KS) << 9) + lane * 8;      \
    (BR)[0] = *(const s16x8*)(_sr);                                             \
    (BR)[1] = *(const s16x8*)(_sr + (1 << 14));                                 \
  }

// 512-wide GEMM, 32x32x16 MFMA: wave = 64 rows x 64 cols = 2x2 tiles of 32x32.
// A from LDS buf (b128, uniform bank spread = conflict-free); B all-register,
// double-buffered 2-deep (bregA even ks, bregB odd ks). 128 MFMA @ ~8.07cyc
// vs 256 @ ~4.85 for 16x16x32: -16% MFMA issue cycles.
// Prologue LOAD_B2(BP,0,bregA); LOAD_B2(BP,1,bregB) must run BEFORE entry.
#define GEMM512_32(BP)                                                          \
  {                                                                             \
    _Pragma("unroll") for (int mt = 0; mt < 2; ++mt)                            \
      _Pragma("unroll") for (int nt = 0; nt < 2; ++nt)                          \
        acc[mt][nt] = zero16();                                                 \
    for (int ks2 = 0; ks2 < 16; ++ks2) {                                        \
      const int e = ks2 * 2;                                                    \
      {                                                                         \
        s16x8 a[2];                                                             \
        _Pragma("unroll")                                                       \
        for (int mt = 0; mt < 2; ++mt)                                          \
          a[mt] = *(const s16x8*)(buf + (mt * 32 + l31) * AST + e * 16 + q5 * 8); \
        _Pragma("unroll")                                                       \
        for (int nt = 0; nt < 2; ++nt)                                          \
          _Pragma("unroll")                                                     \
          for (int mt = 0; mt < 2; ++mt)                                        \
            acc[mt][nt] = MFMA32(a[mt], bregA[nt], acc[mt][nt]);                \
        if (ks2 < 15) LOAD_B2(BP, e + 2, bregA);                                \
      }                                                                         \
      const int o = e + 1;                                                      \
      {                                                                         \
        s16x8 a[2];                                                             \
        _Pragma("unroll")                                                       \
        for (int mt = 0; mt < 2; ++mt)                                          \
          a[mt] = *(const s16x8*)(buf + (mt * 32 + l31) * AST + o * 16 + q5 * 8); \
        _Pragma("unroll")                                                       \
        for (int nt = 0; nt < 2; ++nt)                                          \
          _Pragma("unroll")                                                     \
          for (int mt = 0; mt < 2; ++mt)                                        \
            acc[mt][nt] = MFMA32(a[mt], bregB[nt], acc[mt][nt]);                \
        if (ks2 < 15) LOAD_B2(BP, o + 2, bregB);                                \
      }                                                                         \
    }                                                                           \
  }

// block=512 (8 waves), wave = 64x64 slice as 2x2 of 32x32.
// D-layout (m74/m101): col = lane&31, row = (reg&3) + 8*(reg>>2) + 4*(lane>>5).
// Epilogue scalar u16 writes: bank = 16*q5 + (l31>>1) + const -> 32 distinct
// banks, even/odd l31 share a dword -> conflict-free (unlike the 16x16 layout).
// VGPR: acc 64(AGPR) + h-packs 64 + breg 16 + frags/addr -> fits @(512,2).
__global__ __launch_bounds__(512, 2) void hnn_fused(
    const float* __restrict__ x,
    const float* __restrict__ bias0,
    const float* __restrict__ bias1,
    const float* __restrict__ bias2,
    const float* __restrict__ W3,
    const u16* __restrict__ ws,
    float* __restrict__ out)
{
  const u16* p0f = ws;
  const u16* p0b = p0f + D_IN * H_DIM;
  const u16* p1f = p0b + D_IN * H_DIM;
  const u16* p1b = p1f + H_DIM * H_DIM;
  const u16* p2f = p1b + H_DIM * H_DIM;
  const u16* p2b = p2f + H_DIM * H_DIM;

  __shared__ __align__(16) u16 xs[M_TILE * XST];    // 9.0 KB
  __shared__ __align__(16) u16 buf[M_TILE * AST];   // 65.0 KB (activations [row][col])

  const int tid  = threadIdx.x;
  const int wave = tid >> 6;      // 0..7
  const int lane = tid & 63;
  const int ln   = lane & 15;     // 16x16 indices (GEMM5)
  const int q    = lane >> 4;
  const int l31  = lane & 31;     // 32x32 indices
  const int q5   = lane >> 5;
  const int nwb  = wave * 64;     // wave's 64-col (feature) slice
  const int row0 = blockIdx.x * M_TILE;

  // ---- stage x tile: 64x64 fp32 -> bf16 LDS (512 thr x 8 elems) ----
  {
    int r = tid >> 3, c = (tid & 7) * 8;
    const float4* src = (const float4*)(x + (size_t)(row0 + r) * D_IN + c);
    float4 f0 = src[0];
    float4 f1 = src[1];
    unsigned pk0 = (unsigned)f2bf(f0.x) | ((unsigned)f2bf(f0.y) << 16);
    unsigned pk1 = (unsigned)f2bf(f0.z) | ((unsigned)f2bf(f0.w) << 16);
    unsigned pk2 = (unsigned)f2bf(f1.x) | ((unsigned)f2bf(f1.y) << 16);
    unsigned pk3 = (unsigned)f2bf(f1.z) | ((unsigned)f2bf(f1.w) << 16);
    uint4* dst = (uint4*)(xs + r * XST + c);
    *dst = make_uint4(pk0, pk1, pk2, pk3);
  }
  __syncthreads();

  f32x16 acc[2][2];
  s16x8 bregA[2], bregB[2];   // register-B double buffer
  unsigned h0p[2][2][8];      // h0 bf16x2-packed in D-reg order (for tanh' in bwd)
  unsigned h1p[2][2][8];

  // ================ GEMM0: z0 = x @ W0  (K=64, register-B, 32x32x16) ================
  #pragma unroll
  for (int mt = 0; mt < 2; ++mt)
    #pragma unroll
    for (int nt = 0; nt < 2; ++nt) acc[mt][nt] = zero16();
  {
    const u16* bpw0 = p0f + ((size_t)wave << 12) + lane * 8;  // ((2w+nt)*4+ks)*512
    #pragma unroll
    for (int ks = 0; ks < 4; ++ks) {
      s16x8 a[2];
      #pragma unroll
      for (int mt = 0; mt < 2; ++mt)
        a[mt] = *(const s16x8*)(xs + (mt * 32 + l31) * XST + ks * 16 + q5 * 8);
      #pragma unroll
      for (int nt = 0; nt < 2; ++nt) {
        s16x8 b = *(const s16x8*)(bpw0 + (nt << 11) + (ks << 9));
        #pragma unroll
        for (int mt = 0; mt < 2; ++mt)
          acc[mt][nt] = MFMA32(a[mt], b, acc[mt][nt]);
      }
    }
  }
  LOAD_B2(p1f, 0, bregA);   // prefetch GEMM1 ks 0,1; overlaps epilogue VALU
  LOAD_B2(p1f, 1, bregB);
  // epilogue: h0 = tanh(z0+b0) -> regs (packed) + buf
  {
    float bv[2];
    #pragma unroll
    for (int nt = 0; nt < 2; ++nt) bv[nt] = bias0[nwb + nt * 32 + l31];
    #pragma unroll
    for (int mt = 0; mt < 2; ++mt)
      #pragma unroll
      for (int nt = 0; nt < 2; ++nt) {
        int col = nwb + nt * 32 + l31;
        u16* bp = buf + (mt * 32 + q5 * 4) * AST + col;
        #pragma unroll
        for (int g = 0; g < 4; ++g) {
          u16 u[4];
          #pragma unroll
          for (int r = 0; r < 4; ++r) {
            float th = fast_tanh(acc[mt][nt][g * 4 + r] + bv[nt]);
            u[r] = f2bf(th);
            bp[(g * 8 + r) * AST] = u[r];
          }
          h0p[mt][nt][g * 2]     = (unsigned)u[0] | ((unsigned)u[1] << 16);
          h0p[mt][nt][g * 2 + 1] = (unsigned)u[2] | ((unsigned)u[3] << 16);
        }
      }
  }
  __syncthreads();

  // ================ GEMM1: z1 = h0 @ W1 ================
  GEMM512_32(p1f);
  __syncthreads();          // all waves done reading h0 (buf)
  LOAD_B2(p2f, 0, bregA);   // prefetch GEMM2
  LOAD_B2(p2f, 1, bregB);
  {
    float bv[2];
    #pragma unroll
    for (int nt = 0; nt < 2; ++nt) bv[nt] = bias1[nwb + nt * 32 + l31];
    #pragma unroll
    for (int mt = 0; mt < 2; ++mt)
      #pragma unroll
      for (int nt = 0; nt < 2; ++nt) {
        int col = nwb + nt * 32 + l31;
        u16* bp = buf + (mt * 32 + q5 * 4) * AST + col;
        #pragma unroll
        for (int g = 0; g < 4; ++g) {
          u16 u[4];
          #pragma unroll
          for (int r = 0; r < 4; ++r) {
            float th = fast_tanh(acc[mt][nt][g * 4 + r] + bv[nt]);
            u[r] = f2bf(th);
            bp[(g * 8 + r) * AST] = u[r];
          }
          h1p[mt][nt][g * 2]     = (unsigned)u[0] | ((unsigned)u[1] << 16);
          h1p[mt][nt][g * 2 + 1] = (unsigned)u[2] | ((unsigned)u[3] << 16);
        }
      }
  }
  __syncthreads();

  // ================ GEMM2: z2 = h1 @ W2 ; gz2 = W3*(1-h2^2) ================
  GEMM512_32(p2f);
  __syncthreads();
  LOAD_B2(p2b, 0, bregA);   // prefetch GEMM3
  LOAD_B2(p2b, 1, bregB);
  {
    float bv[2], w3v[2];
    #pragma unroll
    for (int nt = 0; nt < 2; ++nt) {
      bv[nt]  = bias2[nwb + nt * 32 + l31];
      w3v[nt] = W3[nwb + nt * 32 + l31];
    }
    #pragma unroll
    for (int mt = 0; mt < 2; ++mt)
      #pragma unroll
      for (int nt = 0; nt < 2; ++nt) {
        int col = nwb + nt * 32 + l31;
        u16* bp = buf + (mt * 32 + q5 * 4) * AST + col;
        #pragma unroll
        for (int g = 0; g < 4; ++g)
          #pragma unroll
          for (int r = 0; r < 4; ++r) {
            float th = fast_tanh(acc[mt][nt][g * 4 + r] + bv[nt]);
            float gz = w3v[nt] * (1.0f - th * th);
            bp[(g * 8 + r) * AST] = f2bf(gz);
          }
      }
  }
  __syncthreads();

  // ================ GEMM3: g1 = gz2 @ W2^T ; gz1 = g1*(1-h1^2) ================
  GEMM512_32(p2b);
  __syncthreads();
  LOAD_B2(p1b, 0, bregA);   // prefetch GEMM4
  LOAD_B2(p1b, 1, bregB);
  #pragma unroll
  for (int mt = 0; mt < 2; ++mt)
    #pragma unroll
    for (int nt = 0; nt < 2; ++nt) {
      int col = nwb + nt * 32 + l31;
      u16* bp = buf + (mt * 32 + q5 * 4) * AST + col;
      #pragma unroll
      for (int g = 0; g < 4; ++g)
        #pragma unroll
        for (int r = 0; r < 4; ++r) {
          unsigned pk = h1p[mt][nt][g * 2 + (r >> 1)];
          float hh = bfb2f((r & 1) ? (pk >> 16) : (pk & 0xffffu));
          float gz = acc[mt][nt][g * 4 + r] * (1.0f - hh * hh);
          bp[(g * 8 + r) * AST] = f2bf(gz);
        }
    }
  __syncthreads();

  // ================ GEMM4: g0 = gz1 @ W1^T ; gz0 = g0*(1-h0^2) ================
  GEMM512_32(p1b);
  __syncthreads();
  #pragma unroll
  for (int mt = 0; mt < 2; ++mt)
    #pragma unroll
    for (int nt = 0; nt < 2; ++nt) {
      int col = nwb + nt * 32 + l31;
      u16* bp = buf + (mt * 32 + q5 * 4) * AST + col;
      #pragma unroll
      for (int g = 0; g < 4; ++g)
        #pragma unroll
        for (int r = 0; r < 4; ++r) {
          unsigned pk = h0p[mt][nt][g * 2 + (r >> 1)];
          float hh = bfb2f((r & 1) ? (pk >> 16) : (pk & 0xffffu));
          float gz = acc[mt][nt][g * 4 + r] * (1.0f - hh * hh);
          bp[(g * 8 + r) * AST] = f2bf(gz);
        }
    }
  __syncthreads();

  // ================ GEMM5: gradH = gz0 @ W0^T (64x64), 16x16x32, symplectic ====
  // 8 waves x two 16x16 tiles: row tile = wave&3, col half = wave>>2.
  // Uses p0b (old 16-style pack); buf layout is plain [row][col] so mixed
  // MFMA shapes are fine.
  {
    f32x4 acc5[2];
    acc5[0] = (f32x4){0.f, 0.f, 0.f, 0.f};
    acc5[1] = (f32x4){0.f, 0.f, 0.f, 0.f};
    const int mt5 = wave & 3;                  // row tile 0..3
    const int nb5 = (wave >> 2) * 32;          // gradH column base (0 or 32)
    const u16* bp5 = p0b + ((wave >> 2) << 14) + lane * 8;  // ntg5*16kc*512
    #pragma unroll 2
    for (int kc = 0; kc < 16; ++kc) {
      s16x8 a = *(const s16x8*)(buf + (mt5 * 16 + ln) * AST + kc * 32 + q * 8);
      #pragma unroll
      for (int nt = 0; nt < 2; ++nt) {
        s16x8 b = *(const s16x8*)(bp5 + (nt << 13) + (kc << 9));
        acc5[nt] = MFMA_BF16(a, b, acc5[nt]);
      }
    }
    #pragma unroll
    for (int nt = 0; nt < 2; ++nt) {
      int g = nb5 + nt * 16 + ln;                 // gradH column
      int c = (g < 32) ? g + 32 : g - 32;         // out = concat(gradH[:,32:], -gradH[:,:32])
      float s = (g < 32) ? -1.0f : 1.0f;
      #pragma unroll
      for (int r = 0; r < 4; ++r) {
        int grow = row0 + mt5 * 16 + q * 4 + r;
        out[(size_t)grow * 64 + c] = s * acc5[nt][r];
      }
    }
  }
}

extern "C" void kernel_launch(void* const* d_in, const int* in_sizes, int n_in,
                              void* d_out, int out_size, void* d_ws, size_t ws_size,
                              hipStream_t stream) {
  // setup_inputs order: t, x, W0, b0, W1, b1, W2, b2, W3, b3
  const float* x  = (const float*)d_in[1];
  const float* W0 = (const float*)d_in[2];
  const float* b0 = (const float*)d_in[3];
  const float* W1 = (const float*)d_in[4];
  const float* b1 = (const float*)d_in[5];
  const float* W2 = (const float*)d_in[6];
  const float* b2 = (const float*)d_in[7];
  const float* W3 = (const float*)d_in[8];
  u16* ws = (u16*)d_ws;
  float* out = (float*)d_out;

  prep_weights<<<136, 256, 0, stream>>>(W0, W1, W2, ws);
  hnn_fused<<<65536 / M_TILE, 512, 0, stream>>>(x, b0, b1, b2, W3, ws, out);
}

// Round 6
// 223.863 us; speedup vs baseline: 1.1615x; 1.1615x over previous
//
#include <hip/hip_runtime.h>
#include <hip/hip_bf16.h>

typedef unsigned short u16;
typedef short s16x8 __attribute__((ext_vector_type(8)));
typedef float f32x4 __attribute__((ext_vector_type(4)));

#define MFMA_BF16(a, b, c) __builtin_amdgcn_mfma_f32_16x16x32_bf16((a), (b), (c), 0, 0, 0)

static constexpr int D_IN   = 64;
static constexpr int H_DIM  = 512;
static constexpr int M_TILE = 64;
static constexpr int AST    = 520;  // LDS row stride (bf16): b128 A-reads conflict-free
static constexpr int XST    = 72;   // LDS row stride for x tile

__device__ __forceinline__ u16 f2bf(float f) {
  unsigned u = __builtin_bit_cast(unsigned, f);
  u += 0x7fffu + ((u >> 16) & 1u);   // RNE
  return (u16)(u >> 16);
}
__device__ __forceinline__ float bfb2f(unsigned bits16) {
  return __builtin_bit_cast(float, bits16 << 16);
}
__device__ __forceinline__ float fast_tanh(float x) {
  float e = __expf(2.0f * x);
  return 1.0f - 2.0f * __builtin_amdgcn_rcpf(e + 1.0f);
}

// ---- prep: fp32 weights -> bf16, packed in MFMA-B-fragment order ----
// For each (ntg = 16-col tile, kc = 32-wide K chunk): 512 elems stored as
// lane*8 contiguous, lane=(q*16+ln), elem j -> B[k=kc*32+q*8+j][n=ntg*16+ln].
// ws layout (bf16): p0f[64x512] p0b[512x64] p1f p1b p2f p2b  (~2.2MB)
// Tiled LDS transpose, one block per 64x64 source tile (136 tiles).
__global__ __launch_bounds__(256) void prep_weights(const float* __restrict__ W0,
                                                    const float* __restrict__ W1,
                                                    const float* __restrict__ W2,
                                                    u16* __restrict__ ws) {
  u16* p0f = ws;                       // fwd W0: K=64,  N=512
  u16* p0b = p0f + D_IN * H_DIM;       // bwd W0^T: K=512, N=64
  u16* p1f = p0b + D_IN * H_DIM;
  u16* p1b = p1f + H_DIM * H_DIM;
  u16* p2f = p1b + H_DIM * H_DIM;
  u16* p2b = p2f + H_DIM * H_DIM;

  __shared__ __align__(16) u16 tile[64 * 72];   // 9.0 KB, stride 72 u16 (144B)

  int b = blockIdx.x;
  const float* src;
  u16 *dstf, *dstb;
  int rb, cb;
  bool isW0;
  if (b < 64) {
    src = W1; dstf = p1f; dstb = p1b; rb = b >> 3; cb = b & 7; isW0 = false;
  } else if (b < 128) {
    src = W2; dstf = p2f; dstb = p2b; rb = (b - 64) >> 3; cb = (b - 64) & 7; isW0 = false;
  } else {
    src = W0; dstf = p0f; dstb = p0b; rb = 0; cb = b - 128; isW0 = true;
  }

  const int tid = threadIdx.x;

  // ---- stage 64x64 fp32 tile -> bf16 LDS (coalesced: 4x float4 per thread) ----
  {
    int r = tid >> 2, cc = (tid & 3) * 16;
    const float4* s4 = (const float4*)(src + (size_t)(rb * 64 + r) * 512 + cb * 64 + cc);
    unsigned pk[8];
    #pragma unroll
    for (int v = 0; v < 4; ++v) {
      float4 f = s4[v];
      pk[v * 2]     = (unsigned)f2bf(f.x) | ((unsigned)f2bf(f.y) << 16);
      pk[v * 2 + 1] = (unsigned)f2bf(f.z) | ((unsigned)f2bf(f.w) << 16);
    }
    uint4* d = (uint4*)(tile + r * 72 + cc);
    d[0] = make_uint4(pk[0], pk[1], pk[2], pk[3]);
    d[1] = make_uint4(pk[4], pk[5], pk[6], pk[7]);
  }
  __syncthreads();

  const int c   = tid >> 6;          // 0..3: which ntg within this tile
  const int kcl = (tid >> 5) & 1;    // which 32-wide K half of this tile
  const int ls  = (tid * 2) & 63;    // even lane-slot; this thread does ls, ls+1
  const int q   = ls >> 4;
  const int ln  = ls & 15;

  // ---- fwd pack ----
  {
    __align__(16) u16 o[16];
    #pragma unroll
    for (int half = 0; half < 2; ++half)
      #pragma unroll
      for (int j = 0; j < 8; ++j)
        o[half * 8 + j] = tile[(kcl * 32 + q * 8 + j) * 72 + c * 16 + ln + half];
    int ntg   = 4 * cb + c;
    int kc    = 2 * rb + kcl;
    int chunk = isW0 ? (ntg * 2 + kc) : (ntg * 16 + kc);
    u16* dp = dstf + ((size_t)chunk * 64 + ls) * 8;
    *(uint4*)dp       = *(const uint4*)o;
    *(uint4*)(dp + 8) = *(const uint4*)(o + 8);
  }

  // ---- bwd pack ----
  {
    const u16* rp = tile + (c * 16 + ln) * 72 + kcl * 32 + q * 8;
    s16x8 r0 = *(const s16x8*)rp;
    s16x8 r1 = *(const s16x8*)(rp + 72);
    int ntg = 4 * rb + c;
    int kc  = 2 * cb + kcl;
    u16* dp = dstb + ((size_t)(ntg * 16 + kc) * 64 + ls) * 8;
    *(s16x8*)dp       = r0;
    *(s16x8*)(dp + 8) = r1;
  }
}

// Load this wave's 4 B-tiles of k-chunk KC straight into VGPRs (BR[4]).
#define LOAD_B4(BP, KC, BR)                                                     \
  {                                                                             \
    const u16* _sr = (BP) + ((size_t)wave << 15) + ((KC) << 9) + lane * 8;      \
    _Pragma("unroll")                                                           \
    for (int s = 0; s < 4; ++s)                                                 \
      (BR)[s] = *(const s16x8*)(_sr + (s << 13));                               \
  }

// 512-wide GEMM K-loop (round-0 structure): wave = 64 rows x 64 cols.
// A from LDS buffer RB (b128, conflict-free); B all-register, 2-deep dbuf.
#define GEMM512_REG(BP, RB)                                                     \
  {                                                                             \
    _Pragma("unroll") for (int mt = 0; mt < 4; ++mt)                            \
      _Pragma("unroll") for (int nt = 0; nt < 4; ++nt)                          \
        acc[mt][nt] = (f32x4){0.f, 0.f, 0.f, 0.f};                              \
    for (int kc2 = 0; kc2 < 8; ++kc2) {                                         \
      const int e = kc2 * 2;                                                    \
      {                                                                         \
        s16x8 a[4];                                                             \
        _Pragma("unroll")                                                       \
        for (int mt = 0; mt < 4; ++mt)                                          \
          a[mt] = *(const s16x8*)((RB) + (mt * 16 + ln) * AST + e * 32 + q * 8);\
        _Pragma("unroll")                                                       \
        for (int nt = 0; nt < 4; ++nt)                                          \
          _Pragma("unroll")                                                     \
          for (int mt = 0; mt < 4; ++mt)                                        \
            acc[mt][nt] = MFMA_BF16(a[mt], bregA[nt], acc[mt][nt]);             \
        if (kc2 < 7) LOAD_B4(BP, e + 2, bregA);                                 \
      }                                                                         \
      const int o = e + 1;                                                      \
      {                                                                         \
        s16x8 a[4];                                                             \
        _Pragma("unroll")                                                       \
        for (int mt = 0; mt < 4; ++mt)                                          \
          a[mt] = *(const s16x8*)((RB) + (mt * 16 + ln) * AST + o * 32 + q * 8);\
        _Pragma("unroll")                                                       \
        for (int nt = 0; nt < 4; ++nt)                                          \
          _Pragma("unroll")                                                     \
          for (int mt = 0; mt < 4; ++mt)                                        \
            acc[mt][nt] = MFMA_BF16(a[mt], bregB[nt], acc[mt][nt]);             \
        if (kc2 < 7) LOAD_B4(BP, o + 2, bregB);                                 \
      }                                                                         \
    }                                                                           \
  }

// block=512 (8 waves), wave = 64x64 slice. PING-PONG activation LDS:
// phase n reads bufX, writes bufY, ONE barrier -> 6 barriers total (was 11).
// Correct: a writer of bufX (phase n+2's epilogue) is past the phase-n+1
// barrier, which every reader of bufX (phase n's GEMM) reached only after
// finishing its reads. Occupancy is 1 block/CU regardless (measured ~22%),
// so the extra 66KB LDS is free.
__global__ __launch_bounds__(512, 2) void hnn_fused(
    const float* __restrict__ x,
    const float* __restrict__ bias0,
    const float* __restrict__ bias1,
    const float* __restrict__ bias2,
    const float* __restrict__ W3,
    const u16* __restrict__ ws,
    float* __restrict__ out)
{
  const u16* p0f = ws;
  const u16* p0b = p0f + D_IN * H_DIM;
  const u16* p1f = p0b + D_IN * H_DIM;
  const u16* p1b = p1f + H_DIM * H_DIM;
  const u16* p2f = p1b + H_DIM * H_DIM;
  const u16* p2b = p2f + H_DIM * H_DIM;

  __shared__ __align__(16) u16 xs[M_TILE * XST];     // 9.0 KB
  __shared__ __align__(16) u16 bufA[M_TILE * AST];   // 65.0 KB
  __shared__ __align__(16) u16 bufB[M_TILE * AST];   // 65.0 KB

  const int tid  = threadIdx.x;
  const int wave = tid >> 6;      // 0..7
  const int lane = tid & 63;
  const int ln   = lane & 15;
  const int q    = lane >> 4;
  const int nwb  = wave * 64;     // wave's 64-col slice
  const int row0 = blockIdx.x * M_TILE;

  // ---- stage x tile: 64x64 fp32 -> bf16 LDS (512 thr x 8 elems) ----
  {
    int r = tid >> 3, c = (tid & 7) * 8;
    const float4* src = (const float4*)(x + (size_t)(row0 + r) * D_IN + c);
    float4 f0 = src[0];
    float4 f1 = src[1];
    u16* dst = xs + r * XST + c;
    dst[0] = f2bf(f0.x); dst[1] = f2bf(f0.y); dst[2] = f2bf(f0.z); dst[3] = f2bf(f0.w);
    dst[4] = f2bf(f1.x); dst[5] = f2bf(f1.y); dst[6] = f2bf(f1.z); dst[7] = f2bf(f1.w);
  }
  __syncthreads();

  f32x4 acc[4][4];
  s16x8 bregA[4], bregB[4];   // register-B double buffer
  unsigned h0p[4][4][2];      // h0 bf16x2-packed, C-layout (for tanh' in bwd)
  unsigned h1p[4][4][2];
  float bias[4];

  // ================ GEMM0: z0 = x @ W0  (K=64, register-B) ================
  #pragma unroll
  for (int nt = 0; nt < 4; ++nt) bias[nt] = bias0[nwb + nt * 16 + ln];
  #pragma unroll
  for (int mt = 0; mt < 4; ++mt)
    #pragma unroll
    for (int nt = 0; nt < 4; ++nt) acc[mt][nt] = (f32x4){0.f, 0.f, 0.f, 0.f};
  {
    const u16* bpw0 = p0f + (wave << 12) + lane * 8;  // (wave*4 ntg) * 2 kc * 512
    #pragma unroll
    for (int kc = 0; kc < 2; ++kc) {
      s16x8 a[4];
      #pragma unroll
      for (int mt = 0; mt < 4; ++mt)
        a[mt] = *(const s16x8*)(xs + (mt * 16 + ln) * XST + kc * 32 + q * 8);
      #pragma unroll
      for (int nt = 0; nt < 4; ++nt) {
        s16x8 b = *(const s16x8*)(bpw0 + (nt << 10) + (kc << 9));
        #pragma unroll
        for (int mt = 0; mt < 4; ++mt)
          acc[mt][nt] = MFMA_BF16(a[mt], b, acc[mt][nt]);
      }
    }
  }
  LOAD_B4(p1f, 0, bregA);   // prefetch GEMM1 kc 0,1; overlaps epilogue VALU
  LOAD_B4(p1f, 1, bregB);
  // epi0: h0 = tanh(z0+b0) -> regs + bufA (first use)
  #pragma unroll
  for (int mt = 0; mt < 4; ++mt)
    #pragma unroll
    for (int nt = 0; nt < 4; ++nt) {
      int col = nwb + nt * 16 + ln;
      u16 u[4];
      #pragma unroll
      for (int r = 0; r < 4; ++r) {
        float th = fast_tanh(acc[mt][nt][r] + bias[nt]);
        u[r] = f2bf(th);
        bufA[(mt * 16 + q * 4 + r) * AST + col] = u[r];
      }
      h0p[mt][nt][0] = (unsigned)u[0] | ((unsigned)u[1] << 16);
      h0p[mt][nt][1] = (unsigned)u[2] | ((unsigned)u[3] << 16);
    }
  __syncthreads();

  // ================ GEMM1: z1 = h0 @ W1  (reads A, writes B) ================
  #pragma unroll
  for (int nt = 0; nt < 4; ++nt) bias[nt] = bias1[nwb + nt * 16 + ln];
  GEMM512_REG(p1f, bufA);
  LOAD_B4(p2f, 0, bregA);   // prefetch GEMM2
  LOAD_B4(p2f, 1, bregB);
  #pragma unroll
  for (int mt = 0; mt < 4; ++mt)
    #pragma unroll
    for (int nt = 0; nt < 4; ++nt) {
      int col = nwb + nt * 16 + ln;
      u16 u[4];
      #pragma unroll
      for (int r = 0; r < 4; ++r) {
        float th = fast_tanh(acc[mt][nt][r] + bias[nt]);
        u[r] = f2bf(th);
        bufB[(mt * 16 + q * 4 + r) * AST + col] = u[r];
      }
      h1p[mt][nt][0] = (unsigned)u[0] | ((unsigned)u[1] << 16);
      h1p[mt][nt][1] = (unsigned)u[2] | ((unsigned)u[3] << 16);
    }
  __syncthreads();

  // ================ GEMM2: z2 = h1 @ W2 ; gz2 = W3*(1-h2^2)  (reads B, writes A) ====
  #pragma unroll
  for (int nt = 0; nt < 4; ++nt) bias[nt] = bias2[nwb + nt * 16 + ln];
  float w3v[4];
  #pragma unroll
  for (int nt = 0; nt < 4; ++nt) w3v[nt] = W3[nwb + nt * 16 + ln];
  GEMM512_REG(p2f, bufB);
  LOAD_B4(p2b, 0, bregA);   // prefetch GEMM3
  LOAD_B4(p2b, 1, bregB);
  #pragma unroll
  for (int mt = 0; mt < 4; ++mt)
    #pragma unroll
    for (int nt = 0; nt < 4; ++nt) {
      int col = nwb + nt * 16 + ln;
      #pragma unroll
      for (int r = 0; r < 4; ++r) {
        float th = fast_tanh(acc[mt][nt][r] + bias[nt]);
        float gz = w3v[nt] * (1.0f - th * th);
        bufA[(mt * 16 + q * 4 + r) * AST + col] = f2bf(gz);
      }
    }
  __syncthreads();

  // ================ GEMM3: g1 = gz2 @ W2^T ; gz1 = g1*(1-h1^2)  (reads A, writes B) ==
  GEMM512_REG(p2b, bufA);
  LOAD_B4(p1b, 0, bregA);   // prefetch GEMM4
  LOAD_B4(p1b, 1, bregB);
  #pragma unroll
  for (int mt = 0; mt < 4; ++mt)
    #pragma unroll
    for (int nt = 0; nt < 4; ++nt) {
      int col = nwb + nt * 16 + ln;
      unsigned pa = h1p[mt][nt][0], pb = h1p[mt][nt][1];
      float hh[4] = { bfb2f(pa & 0xffffu), bfb2f(pa >> 16),
                      bfb2f(pb & 0xffffu), bfb2f(pb >> 16) };
      #pragma unroll
      for (int r = 0; r < 4; ++r) {
        float gz = acc[mt][nt][r] * (1.0f - hh[r] * hh[r]);
        bufB[(mt * 16 + q * 4 + r) * AST + col] = f2bf(gz);
      }
    }
  __syncthreads();

  // ================ GEMM4: g0 = gz1 @ W1^T ; gz0 = g0*(1-h0^2)  (reads B, writes A) ==
  GEMM512_REG(p1b, bufB);
  __syncthreads();   // wait: all waves done reading bufB? not needed for bufA write;
                     // placed here only to order epi4's bufA writes after GEMM3's
                     // bufA reads -- but that ordering is already given by the
                     // barrier after epi3. Removed: see below.
  // (barrier above is redundant by the ping-pong argument; kept OUT:)
  #pragma unroll
  for (int mt = 0; mt < 4; ++mt)
    #pragma unroll
    for (int nt = 0; nt < 4; ++nt) {
      int col = nwb + nt * 16 + ln;
      unsigned pa = h0p[mt][nt][0], pb = h0p[mt][nt][1];
      float hh[4] = { bfb2f(pa & 0xffffu), bfb2f(pa >> 16),
                      bfb2f(pb & 0xffffu), bfb2f(pb >> 16) };
      #pragma unroll
      for (int r = 0; r < 4; ++r) {
        float gz = acc[mt][nt][r] * (1.0f - hh[r] * hh[r]);
        bufA[(mt * 16 + q * 4 + r) * AST + col] = f2bf(gz);
      }
    }
  __syncthreads();

  // ================ GEMM5: gradH = gz0 @ W0^T (64x64), symplectic store ======
  {
    f32x4 acc5[2];
    acc5[0] = (f32x4){0.f, 0.f, 0.f, 0.f};
    acc5[1] = (f32x4){0.f, 0.f, 0.f, 0.f};
    const int mt5 = wave & 3;                  // row tile 0..3
    const int nb5 = (wave >> 2) * 32;          // gradH column base (0 or 32)
    const u16* bp5 = p0b + ((wave >> 2) << 14) + lane * 8;  // ntg5*16kc*512
    #pragma unroll 2
    for (int kc = 0; kc < 16; ++kc) {
      s16x8 a = *(const s16x8*)(bufA + (mt5 * 16 + ln) * AST + kc * 32 + q * 8);
      #pragma unroll
      for (int nt = 0; nt < 2; ++nt) {
        s16x8 b = *(const s16x8*)(bp5 + (nt << 13) + (kc << 9));
        acc5[nt] = MFMA_BF16(a, b, acc5[nt]);
      }
    }
    #pragma unroll
    for (int nt = 0; nt < 2; ++nt) {
      int g = nb5 + nt * 16 + ln;                 // gradH column
      int c = (g < 32) ? g + 32 : g - 32;         // out = concat(gradH[:,32:], -gradH[:,:32])
      float s = (g < 32) ? -1.0f : 1.0f;
      #pragma unroll
      for (int r = 0; r < 4; ++r) {
        int grow = row0 + mt5 * 16 + q * 4 + r;
        out[(size_t)grow * 64 + c] = s * acc5[nt][r];
      }
    }
  }
}

extern "C" void kernel_launch(void* const* d_in, const int* in_sizes, int n_in,
                              void* d_out, int out_size, void* d_ws, size_t ws_size,
                              hipStream_t stream) {
  // setup_inputs order: t, x, W0, b0, W1, b1, W2, b2, W3, b3
  const float* x  = (const float*)d_in[1];
  const float* W0 = (const float*)d_in[2];
  const float* b0 = (const float*)d_in[3];
  const float* W1 = (const float*)d_in[4];
  const float* b1 = (const float*)d_in[5];
  const float* W2 = (const float*)d_in[6];
  const float* b2 = (const float*)d_in[7];
  const float* W3 = (const float*)d_in[8];
  u16* ws = (u16*)d_ws;
  float* out = (float*)d_out;

  prep_weights<<<136, 256, 0, stream>>>(W0, W1, W2, ws);
  hnn_fused<<<65536 / M_TILE, 512, 0, stream>>>(x, b0, b1, b2, W3, ws, out);
}